// Round 6
// baseline (234.095 us; speedup 1.0000x reference)
//
#include <hip/hip_runtime.h>
#include <math.h>

#define BATCH 2
#define SEQ   2048
#define NH    16
#define DH    64
#define DM    1024

typedef __attribute__((ext_vector_type(8))) short bf16x8;
typedef __attribute__((ext_vector_type(8))) unsigned short u16x8;
typedef __attribute__((ext_vector_type(4))) float f32x4;

__device__ __forceinline__ unsigned short f2bf(float f) {
    union { float f; unsigned u; } v; v.f = f;
    unsigned r = v.u + 0x7FFF + ((v.u >> 16) & 1);
    return (unsigned short)(r >> 16);
}
// cheap round-half-up (positive finite inputs; used for softmax weights)
__device__ __forceinline__ unsigned short f2bf_fast(float f) {
    union { float f; unsigned u; } v; v.f = f;
    return (unsigned short)((v.u + 0x8000u) >> 16);
}

// ---------------------------------------------------------------------------
// conv_x: x fp32 [4096][1024] -> bf16
// ---------------------------------------------------------------------------
__global__ __launch_bounds__(256) void conv_x(
    const float* __restrict__ x, unsigned short* __restrict__ xb)
{
    size_t idx = ((size_t)blockIdx.x * 256 + threadIdx.x) * 8;
    float4 a = *(const float4*)(x + idx);
    float4 b = *(const float4*)(x + idx + 4);
    u16x8 o;
    o[0] = f2bf(a.x); o[1] = f2bf(a.y); o[2] = f2bf(a.z); o[3] = f2bf(a.w);
    o[4] = f2bf(b.x); o[5] = f2bf(b.y); o[6] = f2bf(b.z); o[7] = f2bf(b.w);
    *(u16x8*)(xb + idx) = o;
}

// ---------------------------------------------------------------------------
// conv_w: transpose+convert weights to B^T bf16 layouts.
// ---------------------------------------------------------------------------
__global__ __launch_bounds__(256) void conv_w(
    const float* __restrict__ WQ, const float* __restrict__ WK,
    const float* __restrict__ WV, const float* __restrict__ WO,
    unsigned short* __restrict__ Wt, unsigned short* __restrict__ WOt)
{
    __shared__ float sT[64][68];
    const int t = blockIdx.x;
    const int tid = threadIdx.x;

    if (t < 768) {
        int m = t >> 8, rem = t & 255, h = rem >> 4, dblk = rem & 15;
        const float* W = (m == 0) ? WQ : (m == 1) ? WK : WV;
        const float* in = W + (size_t)h * 65536 + dblk * 4096;
#pragma unroll
        for (int it = 0; it < 4; it++) {
            int idx = it * 1024 + tid * 4;
            int r = idx >> 6, c = idx & 63;
            *(float4*)(&sT[r][c]) = *(const float4*)(&in[(size_t)r * 64 + c]);
        }
        __syncthreads();
        unsigned short* out = Wt + (size_t)m * 1048576 + (size_t)h * 65536 + dblk * 64;
#pragma unroll
        for (int it = 0; it < 4; it++) {
            int idx = it * 1024 + tid * 4;
            int e = idx >> 6, d0 = idx & 63;
            ushort4 o;
            unsigned short* op = (unsigned short*)&o;
#pragma unroll
            for (int j = 0; j < 4; j++) op[j] = f2bf(sT[d0 + j][e]);
            *(ushort4*)&out[(size_t)e * 1024 + d0] = o;
        }
    } else {
        int tt = t - 768, rblk = tt >> 4, cblk = tt & 15;
        const float* in = WO + (size_t)rblk * 64 * 1024 + cblk * 64;
#pragma unroll
        for (int it = 0; it < 4; it++) {
            int idx = it * 1024 + tid * 4;
            int r = idx >> 6, c = idx & 63;
            *(float4*)(&sT[r][c]) = *(const float4*)(&in[(size_t)r * 1024 + c]);
        }
        __syncthreads();
        unsigned short* out = WOt + (size_t)cblk * 64 * 1024 + rblk * 64;
#pragma unroll
        for (int it = 0; it < 4; it++) {
            int idx = it * 1024 + tid * 4;
            int d = idx >> 6, he0 = idx & 63;
            ushort4 o;
            unsigned short* op = (unsigned short*)&o;
#pragma unroll
            for (int j = 0; j < 4; j++) op[j] = f2bf(sT[he0 + j][d]);
            *(ushort4*)&out[(size_t)d * 1024 + he0] = o;
        }
    }
}

// ---------------------------------------------------------------------------
// qkv_mfma: xb [4096][1024] bf16 @ Wt[m][h][e][d] -> Q/K bf16 [B][H][S][E],
//           V written TRANSPOSED: Vt [B][H][E][S]
// Q/K use SWAPPED mfma operands (D[m=e][n=s]) so a lane's 4 acc values are
// 4 consecutive e -> packed ushort4 stores into [s][e].
// ---------------------------------------------------------------------------
__global__ __launch_bounds__(256) void qkv_mfma(
    const unsigned short* __restrict__ xb,
    const unsigned short* __restrict__ Wt,
    const float* __restrict__ bQ, const float* __restrict__ bK,
    const float* __restrict__ bV,
    unsigned short* __restrict__ Q, unsigned short* __restrict__ K,
    unsigned short* __restrict__ Vt)
{
    __shared__ __align__(16) unsigned short sA[128 * 72];
    __shared__ __align__(16) unsigned short sB[128 * 72];

    const int rowTile = blockIdx.x;
    const int m  = blockIdx.y >> 3;
    const int hp = blockIdx.y & 7;
    const unsigned short* Wm = Wt + (size_t)m * 1048576 + (size_t)hp * 2 * 65536;

    const int tid  = threadIdx.x;
    const int w    = tid >> 6;
    const int lane = tid & 63;
    const int l15  = lane & 15;
    const int quad = lane >> 4;
    const int rw   = (w & 1) * 64;
    const int cw   = (w >> 1) * 64;
    const int rowBase = rowTile * 128;

    f32x4 acc[4][4];
#pragma unroll
    for (int i = 0; i < 4; i++)
#pragma unroll
        for (int j = 0; j < 4; j++) acc[i][j] = (f32x4){0.f, 0.f, 0.f, 0.f};

    const int sr = tid >> 3;
    const int sc = (tid & 7) * 8;

    for (int k0 = 0; k0 < DM; k0 += 64) {
        __syncthreads();
#pragma unroll
        for (int it = 0; it < 4; it++) {
            int r = it * 32 + sr;
            *(u16x8*)&sA[r * 72 + sc] =
                *(const u16x8*)&xb[(size_t)(rowBase + r) * DM + k0 + sc];
            *(u16x8*)&sB[r * 72 + sc] =
                *(const u16x8*)&Wm[(size_t)r * DM + k0 + sc];
        }
        __syncthreads();
#pragma unroll
        for (int ks = 0; ks < 2; ks++) {
            bf16x8 af[4], bf[4];
#pragma unroll
            for (int i = 0; i < 4; i++)
                af[i] = *(const bf16x8*)&sA[(rw + i * 16 + l15) * 72 + ks * 32 + quad * 8];
#pragma unroll
            for (int j = 0; j < 4; j++)
                bf[j] = *(const bf16x8*)&sB[(cw + j * 16 + l15) * 72 + ks * 32 + quad * 8];
            if (m == 2) {
#pragma unroll
                for (int i = 0; i < 4; i++)
#pragma unroll
                    for (int j = 0; j < 4; j++)
                        acc[i][j] = __builtin_amdgcn_mfma_f32_16x16x32_bf16(
                            af[i], bf[j], acc[i][j], 0, 0, 0);
            } else {
#pragma unroll
                for (int i = 0; i < 4; i++)
#pragma unroll
                    for (int j = 0; j < 4; j++)
                        acc[i][j] = __builtin_amdgcn_mfma_f32_16x16x32_bf16(
                            bf[j], af[i], acc[i][j], 0, 0, 0);
            }
        }
    }

    if (m == 2) {
        // D[m=s][n=e]: lane holds fixed e, 4 consecutive s -> Vt[e][s] packed
#pragma unroll
        for (int j = 0; j < 4; j++) {
            int col = cw + j * 16 + l15;
            int h = hp * 2 + (col >> 6);
            int e = col & 63;
            float bv = bV[h * DH + e];
#pragma unroll
            for (int i = 0; i < 4; i++) {
                int row0 = rowBase + rw + i * 16 + quad * 4;
                int b = row0 >> 11, s0 = row0 & 2047;
                ushort4 o;
                unsigned short* op = (unsigned short*)&o;
#pragma unroll
                for (int r = 0; r < 4; r++) op[r] = f2bf(acc[i][j][r] + bv);
                *(ushort4*)&Vt[(((size_t)b * NH + h) * DH + e) * SEQ + s0] = o;
            }
        }
    } else {
        // D[m=e][n=s]: lane holds fixed s, 4 consecutive e -> [s][e] packed
        const float* bias = (m == 0) ? bQ : bK;
        unsigned short* Out = (m == 0) ? Q : K;
        const float scale = (m == 0) ? 0.125f : 1.0f;
#pragma unroll
        for (int i = 0; i < 4; i++) {
            int row = rowBase + rw + i * 16 + l15;
            int b = row >> 11, s = row & 2047;
#pragma unroll
            for (int j = 0; j < 4; j++) {
                int col0 = cw + j * 16 + quad * 4;
                int h = hp * 2 + (col0 >> 6);
                int e0 = col0 & 63;
                ushort4 o;
                unsigned short* op = (unsigned short*)&o;
#pragma unroll
                for (int r = 0; r < 4; r++)
                    op[r] = f2bf((acc[i][j][r] + bias[h * DH + e0 + r]) * scale);
                *(ushort4*)&Out[(((size_t)b * NH + h) * SEQ + s) * DH + e0] = o;
            }
        }
    }
}

// ---------------------------------------------------------------------------
// attn_mfma v4: balanced pair {i, 31-i} + pipelined staging + LDS dbuf.
//  - every block: exactly 33 tile-computes (perfect balance).
//  - tile kt+1 global->regs issued during tile kt compute; regs->LDS at
//    iteration top; ONE barrier per iteration (ping-pong buffers).
// ---------------------------------------------------------------------------
__device__ __forceinline__ void attn_tile(
    const bf16x8 (&kf)[8], const bf16x8 (&vf)[8], const bf16x8 (&qf)[2],
    unsigned short* __restrict__ sP,
    int kt, int qt, int w, int l15, int quad,
    f32x4 (&O4)[4], float (&l_p)[4])
{
    f32x4 S4[4];
#pragma unroll
    for (int s = 0; s < 4; s++) S4[s] = (f32x4){0.f, 0.f, 0.f, 0.f};
#pragma unroll
    for (int ks = 0; ks < 2; ks++)
#pragma unroll
        for (int sub = 0; sub < 4; sub++)
            S4[sub] = __builtin_amdgcn_mfma_f32_16x16x32_bf16(
                qf[ks], kf[ks * 4 + sub], S4[sub], 0, 0, 0);

    const bool diag = (kt == qt);
#pragma unroll
    for (int sub = 0; sub < 4; sub++) {
#pragma unroll
        for (int r = 0; r < 4; r++) {
            float p = __expf(S4[sub][r]);
            if (diag && (sub * 16 + l15 > w * 16 + quad * 4 + r)) p = 0.f;
            l_p[r] += p;
            sP[(w * 16 + quad * 4 + r) * 72 + sub * 16 + l15] = f2bf_fast(p);
        }
    }
    __builtin_amdgcn_wave_barrier();

#pragma unroll
    for (int ks = 0; ks < 2; ks++) {
        bf16x8 a = *(const bf16x8*)&sP[(w * 16 + l15) * 72 + ks * 32 + quad * 8];
#pragma unroll
        for (int sub = 0; sub < 4; sub++)
            O4[sub] = __builtin_amdgcn_mfma_f32_16x16x32_bf16(
                a, vf[ks * 4 + sub], O4[sub], 0, 0, 0);
    }
    __builtin_amdgcn_wave_barrier();
}

__global__ __launch_bounds__(256) void attn_mfma(
    const unsigned short* __restrict__ Q,    // [B][H][S][E] bf16, pre-scaled
    const unsigned short* __restrict__ K,    // [B][H][S][E] bf16
    const unsigned short* __restrict__ Vt,   // [B][H][E][S] bf16
    unsigned short* __restrict__ Z)          // [B][S][H*E] bf16
{
    __shared__ __align__(16) unsigned short sK[2][64 * 72];
    __shared__ __align__(16) unsigned short sV[2][64 * 72];
    __shared__ __align__(16) unsigned short sPA[64 * 72];
    __shared__ __align__(16) unsigned short sPB[64 * 72];

    const int h   = blockIdx.x & 15;
    const int b   = (blockIdx.x >> 4) & 1;
    const int i   = blockIdx.x >> 5;          // 0..15
    const int qtA = i;
    const int qtB = 31 - i;

    const int tid  = threadIdx.x;
    const int w    = tid >> 6;
    const int lane = tid & 63;
    const int l15  = lane & 15;
    const int quad = lane >> 4;

    const size_t headOff = ((size_t)b * NH + h) * SEQ * DH;
    const unsigned short* Qh  = Q  + headOff;
    const unsigned short* Kh  = K  + headOff;
    const unsigned short* Vth = Vt + headOff;   // [E][S]

    const unsigned short* qrowA =
        Qh + (size_t)(qtA * 64 + w * 16 + l15) * DH + quad * 8;
    const unsigned short* qrowB =
        Qh + (size_t)(qtB * 64 + w * 16 + l15) * DH + quad * 8;
    bf16x8 qA[2], qB[2];
    qA[0] = *(const bf16x8*)(qrowA);  qA[1] = *(const bf16x8*)(qrowA + 32);
    qB[0] = *(const bf16x8*)(qrowB);  qB[1] = *(const bf16x8*)(qrowB + 32);

    f32x4 OA[4], OB[4];
    float lA[4], lB[4];
#pragma unroll
    for (int s = 0; s < 4; s++) {
        OA[s] = (f32x4){0.f, 0.f, 0.f, 0.f};
        OB[s] = (f32x4){0.f, 0.f, 0.f, 0.f};
    }
#pragma unroll
    for (int r = 0; r < 4; r++) { lA[r] = 0.f; lB[r] = 0.f; }

    const int r0 = tid >> 3;          // staging row 0..31
    const int c0 = (tid & 7) * 8;     // staging col (elems)

    // prefetch tile 0 into registers
    u16x8 rK0 = *(const u16x8*)&Kh[(size_t)r0 * DH + c0];
    u16x8 rK1 = *(const u16x8*)&Kh[(size_t)(r0 + 32) * DH + c0];
    u16x8 rV0 = *(const u16x8*)&Vth[(size_t)r0 * SEQ + c0];
    u16x8 rV1 = *(const u16x8*)&Vth[(size_t)(r0 + 32) * SEQ + c0];

    for (int kt = 0; kt <= qtB; kt++) {
        const int p = kt & 1;
        unsigned short* bKp = sK[p];
        unsigned short* bVp = sV[p];
        // regs -> LDS (waits on the in-flight global loads)
        *(u16x8*)&bKp[r0 * 72 + c0]        = rK0;
        *(u16x8*)&bKp[(r0 + 32) * 72 + c0] = rK1;
        *(u16x8*)&bVp[r0 * 72 + c0]        = rV0;
        *(u16x8*)&bVp[(r0 + 32) * 72 + c0] = rV1;
        __syncthreads();

        // issue next tile's global loads (latency hidden by compute below)
        if (kt < qtB) {
            const int k1 = (kt + 1) * 64;
            rK0 = *(const u16x8*)&Kh[(size_t)(k1 + r0) * DH + c0];
            rK1 = *(const u16x8*)&Kh[(size_t)(k1 + r0 + 32) * DH + c0];
            rV0 = *(const u16x8*)&Vth[(size_t)r0 * SEQ + k1 + c0];
            rV1 = *(const u16x8*)&Vth[(size_t)(r0 + 32) * SEQ + k1 + c0];
        }

        bf16x8 kf[8], vf[8];
#pragma unroll
        for (int ks = 0; ks < 2; ks++)
#pragma unroll
            for (int sub = 0; sub < 4; sub++) {
                kf[ks * 4 + sub] = *(const bf16x8*)
                    &bKp[(sub * 16 + l15) * 72 + ks * 32 + quad * 8];
                vf[ks * 4 + sub] = *(const bf16x8*)
                    &bVp[(sub * 16 + l15) * 72 + ks * 32 + quad * 8];
            }

        if (kt <= qtA)
            attn_tile(kf, vf, qA, sPA, kt, qtA, w, l15, quad, OA, lA);
        attn_tile(kf, vf, qB, sPB, kt, qtB, w, l15, quad, OB, lB);
    }

    // epilogue: denominators + stores for both tiles
#pragma unroll
    for (int half = 0; half < 2; half++) {
        const int qt = half ? qtB : qtA;
        f32x4* O4 = half ? OB : OA;
        float* l_p = half ? lB : lA;
        float rl[4];
#pragma unroll
        for (int r = 0; r < 4; r++) {
            float v = l_p[r];
            v += __shfl_xor(v, 1, 64);
            v += __shfl_xor(v, 2, 64);
            v += __shfl_xor(v, 4, 64);
            v += __shfl_xor(v, 8, 64);
            rl[r] = 1.0f / v;
        }
#pragma unroll
        for (int sub = 0; sub < 4; sub++) {
#pragma unroll
            for (int r = 0; r < 4; r++) {
                int q = qt * 64 + w * 16 + quad * 4 + r;
                int col = h * DH + sub * 16 + l15;
                Z[((size_t)b * SEQ + q) * DM + col] = f2bf(O4[sub][r] * rl[r]);
            }
        }
    }
}

// ---------------------------------------------------------------------------
// out_mfma: Zb [4096][1024] bf16 @ WOt [d][he] bf16 -> out fp32 + b_O
// SWAPPED operands: D[m=col][n=row] -> lane holds 4 consecutive cols ->
// coalesced float4 stores.
// ---------------------------------------------------------------------------
__global__ __launch_bounds__(256) void out_mfma(
    const unsigned short* __restrict__ Zb,
    const unsigned short* __restrict__ WOt,
    const float* __restrict__ bO,
    float* __restrict__ out)
{
    __shared__ __align__(16) unsigned short sA[64 * 72];
    __shared__ __align__(16) unsigned short sB[128 * 72];

    const int rowTile = blockIdx.x;
    const int colTile = blockIdx.y;
    const int rowBase = rowTile * 64;
    const int colBase = colTile * 128;

    const int tid  = threadIdx.x;
    const int w    = tid >> 6;
    const int lane = tid & 63;
    const int l15  = lane & 15;
    const int quad = lane >> 4;
    const int rw   = (w & 1) * 32;
    const int cw   = (w >> 1) * 64;

    f32x4 acc[2][4];
#pragma unroll
    for (int i = 0; i < 2; i++)
#pragma unroll
        for (int j = 0; j < 4; j++) acc[i][j] = (f32x4){0.f, 0.f, 0.f, 0.f};

    const int sr = tid >> 3;
    const int sc = (tid & 7) * 8;

    for (int k0 = 0; k0 < DM; k0 += 64) {
        __syncthreads();
#pragma unroll
        for (int it = 0; it < 2; it++) {
            int r = it * 32 + sr;
            *(u16x8*)&sA[r * 72 + sc] =
                *(const u16x8*)&Zb[(size_t)(rowBase + r) * DM + k0 + sc];
        }
#pragma unroll
        for (int it = 0; it < 4; it++) {
            int r = it * 32 + sr;
            *(u16x8*)&sB[r * 72 + sc] =
                *(const u16x8*)&WOt[(size_t)(colBase + r) * DM + k0 + sc];
        }
        __syncthreads();
#pragma unroll
        for (int ks = 0; ks < 2; ks++) {
            bf16x8 af[2], bf[4];
#pragma unroll
            for (int i = 0; i < 2; i++)
                af[i] = *(const bf16x8*)&sA[(rw + i * 16 + l15) * 72 + ks * 32 + quad * 8];
#pragma unroll
            for (int j = 0; j < 4; j++)
                bf[j] = *(const bf16x8*)&sB[(cw + j * 16 + l15) * 72 + ks * 32 + quad * 8];
#pragma unroll
            for (int i = 0; i < 2; i++)
#pragma unroll
                for (int j = 0; j < 4; j++)
                    acc[i][j] = __builtin_amdgcn_mfma_f32_16x16x32_bf16(
                        bf[j], af[i], acc[i][j], 0, 0, 0);
        }
    }

#pragma unroll
    for (int i = 0; i < 2; i++) {
        int row = rowBase + rw + i * 16 + l15;
#pragma unroll
        for (int j = 0; j < 4; j++) {
            int col0 = colBase + cw + j * 16 + quad * 4;
            float4 o;
            o.x = acc[i][j][0] + bO[col0 + 0];
            o.y = acc[i][j][1] + bO[col0 + 1];
            o.z = acc[i][j][2] + bO[col0 + 2];
            o.w = acc[i][j][3] + bO[col0 + 3];
            *(float4*)&out[(size_t)row * DM + col0] = o;
        }
    }
}

// ---------------------------------------------------------------------------
extern "C" void kernel_launch(void* const* d_in, const int* in_sizes, int n_in,
                              void* d_out, int out_size, void* d_ws, size_t ws_size,
                              hipStream_t stream)
{
    const float* x  = (const float*)d_in[0];
    const float* WQ = (const float*)d_in[1];
    const float* WK = (const float*)d_in[2];
    const float* WV = (const float*)d_in[3];
    const float* WO = (const float*)d_in[4];
    const float* bQ = (const float*)d_in[5];
    const float* bK = (const float*)d_in[6];
    const float* bV = (const float*)d_in[7];
    const float* bO = (const float*)d_in[8];
    float* out = (float*)d_out;

    const size_t M4 = 4194304;
    unsigned short* xb  = (unsigned short*)d_ws;       // 4M (reused as Zb)
    unsigned short* Wt  = xb + M4;                     // 3M
    unsigned short* WOt = Wt + 3 * 1048576;            // 1M
    unsigned short* Qw  = WOt + 1048576;               // 4M
    unsigned short* Kw  = Qw + M4;                     // 4M
    unsigned short* Vtw = Kw + M4;                     // 4M (transposed V)
    unsigned short* Zb  = xb;

    conv_x<<<2048, 256, 0, stream>>>(x, xb);
    conv_w<<<1024, 256, 0, stream>>>(WQ, WK, WV, WO, Wt, WOt);

    dim3 g1(32, 24);
    qkv_mfma<<<g1, 256, 0, stream>>>(xb, Wt, bQ, bK, bV, Qw, Kw, Vtw);

    attn_mfma<<<512, 256, 0, stream>>>(Qw, Kw, Vtw, Zb);

    dim3 g3(64, 8);
    out_mfma<<<g3, 256, 0, stream>>>(Zb, WOt, bO, out);
}

// Round 7
// 217.770 us; speedup vs baseline: 1.0750x; 1.0750x over previous
//
#include <hip/hip_runtime.h>
#include <math.h>

#define BATCH 2
#define SEQ   2048
#define NH    16
#define DH    64
#define DM    1024

typedef __attribute__((ext_vector_type(8))) short bf16x8;
typedef __attribute__((ext_vector_type(8))) unsigned short u16x8;
typedef __attribute__((ext_vector_type(4))) float f32x4;

__device__ __forceinline__ unsigned short f2bf(float f) {
    union { float f; unsigned u; } v; v.f = f;
    unsigned r = v.u + 0x7FFF + ((v.u >> 16) & 1);
    return (unsigned short)(r >> 16);
}
// cheap round-half-up (positive finite inputs; softmax weights)
__device__ __forceinline__ unsigned short f2bf_fast(float f) {
    union { float f; unsigned u; } v; v.f = f;
    return (unsigned short)((v.u + 0x8000u) >> 16);
}

// ---------------------------------------------------------------------------
// conv_fused: blockIdx < 2048 -> x fp32 -> bf16 ; else weight transposes.
// ---------------------------------------------------------------------------
__global__ __launch_bounds__(256) void conv_fused(
    const float* __restrict__ x,
    const float* __restrict__ WQ, const float* __restrict__ WK,
    const float* __restrict__ WV, const float* __restrict__ WO,
    unsigned short* __restrict__ xb,
    unsigned short* __restrict__ Wt, unsigned short* __restrict__ WOt)
{
    __shared__ float sT[64][68];
    const int tid = threadIdx.x;

    if (blockIdx.x < 2048) {
        size_t idx = ((size_t)blockIdx.x * 256 + tid) * 8;
        float4 a = *(const float4*)(x + idx);
        float4 b = *(const float4*)(x + idx + 4);
        u16x8 o;
        o[0] = f2bf(a.x); o[1] = f2bf(a.y); o[2] = f2bf(a.z); o[3] = f2bf(a.w);
        o[4] = f2bf(b.x); o[5] = f2bf(b.y); o[6] = f2bf(b.z); o[7] = f2bf(b.w);
        *(u16x8*)(xb + idx) = o;
        return;
    }
    const int t = blockIdx.x - 2048;
    if (t < 768) {
        int m = t >> 8, rem = t & 255, h = rem >> 4, dblk = rem & 15;
        const float* W = (m == 0) ? WQ : (m == 1) ? WK : WV;
        const float* in = W + (size_t)h * 65536 + dblk * 4096;
#pragma unroll
        for (int it = 0; it < 4; it++) {
            int idx = it * 1024 + tid * 4;
            int r = idx >> 6, c = idx & 63;
            *(float4*)(&sT[r][c]) = *(const float4*)(&in[(size_t)r * 64 + c]);
        }
        __syncthreads();
        unsigned short* out = Wt + (size_t)m * 1048576 + (size_t)h * 65536 + dblk * 64;
#pragma unroll
        for (int it = 0; it < 4; it++) {
            int idx = it * 1024 + tid * 4;
            int e = idx >> 6, d0 = idx & 63;
            ushort4 o;
            unsigned short* op = (unsigned short*)&o;
#pragma unroll
            for (int j = 0; j < 4; j++) op[j] = f2bf(sT[d0 + j][e]);
            *(ushort4*)&out[(size_t)e * 1024 + d0] = o;
        }
    } else {
        int tt = t - 768, rblk = tt >> 4, cblk = tt & 15;
        const float* in = WO + (size_t)rblk * 64 * 1024 + cblk * 64;
#pragma unroll
        for (int it = 0; it < 4; it++) {
            int idx = it * 1024 + tid * 4;
            int r = idx >> 6, c = idx & 63;
            *(float4*)(&sT[r][c]) = *(const float4*)(&in[(size_t)r * 1024 + c]);
        }
        __syncthreads();
        unsigned short* out = WOt + (size_t)cblk * 64 * 1024 + rblk * 64;
#pragma unroll
        for (int it = 0; it < 4; it++) {
            int idx = it * 1024 + tid * 4;
            int d = idx >> 6, he0 = idx & 63;
            ushort4 o;
            unsigned short* op = (unsigned short*)&o;
#pragma unroll
            for (int j = 0; j < 4; j++) op[j] = f2bf(sT[he0 + j][d]);
            *(ushort4*)&out[(size_t)d * 1024 + he0] = o;
        }
    }
}

// ---------------------------------------------------------------------------
// qkv_mfma v2: pipelined ping-pong LDS, BK=32, one barrier/iter.
// stride 40 elems (80B): rows 16B-aligned, 8-accesses/bank (b128 floor).
// ---------------------------------------------------------------------------
__global__ __launch_bounds__(256) void qkv_mfma(
    const unsigned short* __restrict__ xb,
    const unsigned short* __restrict__ Wt,
    const float* __restrict__ bQ, const float* __restrict__ bK,
    const float* __restrict__ bV,
    unsigned short* __restrict__ Q, unsigned short* __restrict__ K,
    unsigned short* __restrict__ Vt)
{
    __shared__ __align__(16) unsigned short sA[2][128 * 40];
    __shared__ __align__(16) unsigned short sB[2][128 * 40];

    const int rowTile = blockIdx.x;
    const int m  = blockIdx.y >> 3;
    const int hp = blockIdx.y & 7;
    const unsigned short* Wm = Wt + (size_t)m * 1048576 + (size_t)hp * 2 * 65536;

    const int tid  = threadIdx.x;
    const int w    = tid >> 6;
    const int lane = tid & 63;
    const int l15  = lane & 15;
    const int quad = lane >> 4;
    const int rw   = (w & 1) * 64;
    const int cw   = (w >> 1) * 64;
    const int rowBase = rowTile * 128;

    f32x4 acc[4][4];
#pragma unroll
    for (int i = 0; i < 4; i++)
#pragma unroll
        for (int j = 0; j < 4; j++) acc[i][j] = (f32x4){0.f, 0.f, 0.f, 0.f};

    const int sr = tid >> 2;          // staging row 0..63 (and +64)
    const int sc = (tid & 3) * 8;     // staging col 0..31

    // prefetch k-tile 0
    u16x8 rA0 = *(const u16x8*)&xb[(size_t)(rowBase + sr) * DM + sc];
    u16x8 rA1 = *(const u16x8*)&xb[(size_t)(rowBase + sr + 64) * DM + sc];
    u16x8 rB0 = *(const u16x8*)&Wm[(size_t)sr * DM + sc];
    u16x8 rB1 = *(const u16x8*)&Wm[(size_t)(sr + 64) * DM + sc];

    for (int kt = 0; kt < 32; kt++) {
        const int p = kt & 1;
        unsigned short* pA = sA[p];
        unsigned short* pB = sB[p];
        *(u16x8*)&pA[sr * 40 + sc]        = rA0;
        *(u16x8*)&pA[(sr + 64) * 40 + sc] = rA1;
        *(u16x8*)&pB[sr * 40 + sc]        = rB0;
        *(u16x8*)&pB[(sr + 64) * 40 + sc] = rB1;
        __syncthreads();

        if (kt < 31) {   // prefetch next tile; latency hidden by MFMAs below
            const int k1 = (kt + 1) * 32;
            rA0 = *(const u16x8*)&xb[(size_t)(rowBase + sr) * DM + k1 + sc];
            rA1 = *(const u16x8*)&xb[(size_t)(rowBase + sr + 64) * DM + k1 + sc];
            rB0 = *(const u16x8*)&Wm[(size_t)sr * DM + k1 + sc];
            rB1 = *(const u16x8*)&Wm[(size_t)(sr + 64) * DM + k1 + sc];
        }

        bf16x8 af[4], bf[4];
#pragma unroll
        for (int i = 0; i < 4; i++)
            af[i] = *(const bf16x8*)&pA[(rw + i * 16 + l15) * 40 + quad * 8];
#pragma unroll
        for (int j = 0; j < 4; j++)
            bf[j] = *(const bf16x8*)&pB[(cw + j * 16 + l15) * 40 + quad * 8];
        if (m == 2) {
#pragma unroll
            for (int i = 0; i < 4; i++)
#pragma unroll
                for (int j = 0; j < 4; j++)
                    acc[i][j] = __builtin_amdgcn_mfma_f32_16x16x32_bf16(
                        af[i], bf[j], acc[i][j], 0, 0, 0);
        } else {
#pragma unroll
            for (int i = 0; i < 4; i++)
#pragma unroll
                for (int j = 0; j < 4; j++)
                    acc[i][j] = __builtin_amdgcn_mfma_f32_16x16x32_bf16(
                        bf[j], af[i], acc[i][j], 0, 0, 0);
        }
    }

    if (m == 2) {
        // D[m=s][n=e]: lane holds fixed e, 4 consecutive s -> Vt[e][s] packed
#pragma unroll
        for (int j = 0; j < 4; j++) {
            int col = cw + j * 16 + l15;
            int h = hp * 2 + (col >> 6);
            int e = col & 63;
            float bv = bV[h * DH + e];
#pragma unroll
            for (int i = 0; i < 4; i++) {
                int row0 = rowBase + rw + i * 16 + quad * 4;
                int b = row0 >> 11, s0 = row0 & 2047;
                ushort4 o;
                unsigned short* op = (unsigned short*)&o;
#pragma unroll
                for (int r = 0; r < 4; r++) op[r] = f2bf(acc[i][j][r] + bv);
                *(ushort4*)&Vt[(((size_t)b * NH + h) * DH + e) * SEQ + s0] = o;
            }
        }
    } else {
        // D[m=e][n=s]: lane holds fixed s, 4 consecutive e -> [s][e] packed
        const float* bias = (m == 0) ? bQ : bK;
        unsigned short* Out = (m == 0) ? Q : K;
        const float scale = (m == 0) ? 0.125f : 1.0f;
#pragma unroll
        for (int i = 0; i < 4; i++) {
            int row = rowBase + rw + i * 16 + l15;
            int b = row >> 11, s = row & 2047;
#pragma unroll
            for (int j = 0; j < 4; j++) {
                int col0 = cw + j * 16 + quad * 4;
                int h = hp * 2 + (col0 >> 6);
                int e0 = col0 & 63;
                ushort4 o;
                unsigned short* op = (unsigned short*)&o;
#pragma unroll
                for (int r = 0; r < 4; r++)
                    op[r] = f2bf((acc[i][j][r] + bias[h * DH + e0 + r]) * scale);
                *(ushort4*)&Out[(((size_t)b * NH + h) * SEQ + s) * DH + e0] = o;
            }
        }
    }
}

// ---------------------------------------------------------------------------
// attn_mfma v5: S^T orientation + swapped PV.
//  - S^T = K Q^T via mfma(kf, qf): lane's 4 accs = 4 consecutive KEYS ->
//    softmax writes P as 4 packed ds_write_b64 (was 16 b16); l is one
//    scalar/lane (2 shuffles at end, no per-r reduce).
//  - PV via mfma(vf, pf): lane's 4 accs = 4 consecutive e -> packed Z store,
//    1/l needs no shuffle.
//  - balanced pair {i,31-i}; A/B phases adjacent (no wave_barrier between)
//    so the compiler can interleave the independent tiles.
// ---------------------------------------------------------------------------
__global__ __launch_bounds__(256) void attn_mfma(
    const unsigned short* __restrict__ Q,    // [B][H][S][E] bf16, pre-scaled
    const unsigned short* __restrict__ K,    // [B][H][S][E] bf16
    const unsigned short* __restrict__ Vt,   // [B][H][E][S] bf16
    unsigned short* __restrict__ Z)          // [B][S][H*E] bf16
{
    __shared__ __align__(16) unsigned short sK[2][64 * 72];
    __shared__ __align__(16) unsigned short sV[2][64 * 72];
    __shared__ __align__(16) unsigned short sPA[64 * 72];
    __shared__ __align__(16) unsigned short sPB[64 * 72];

    const int h   = blockIdx.x & 15;
    const int b   = (blockIdx.x >> 4) & 1;
    const int i   = blockIdx.x >> 5;          // 0..15
    const int qtA = i;
    const int qtB = 31 - i;

    const int tid  = threadIdx.x;
    const int w    = tid >> 6;
    const int lane = tid & 63;
    const int l15  = lane & 15;
    const int quad = lane >> 4;

    const size_t headOff = ((size_t)b * NH + h) * SEQ * DH;
    const unsigned short* Qh  = Q  + headOff;
    const unsigned short* Kh  = K  + headOff;
    const unsigned short* Vth = Vt + headOff;   // [E][S]

    const unsigned short* qrowA =
        Qh + (size_t)(qtA * 64 + w * 16 + l15) * DH + quad * 8;
    const unsigned short* qrowB =
        Qh + (size_t)(qtB * 64 + w * 16 + l15) * DH + quad * 8;
    bf16x8 qA[2], qB[2];
    qA[0] = *(const bf16x8*)(qrowA);  qA[1] = *(const bf16x8*)(qrowA + 32);
    qB[0] = *(const bf16x8*)(qrowB);  qB[1] = *(const bf16x8*)(qrowB + 32);

    f32x4 OA[4], OB[4];
#pragma unroll
    for (int s = 0; s < 4; s++) {
        OA[s] = (f32x4){0.f, 0.f, 0.f, 0.f};
        OB[s] = (f32x4){0.f, 0.f, 0.f, 0.f};
    }
    float lAa = 0.f, lBa = 0.f;   // per-lane partial denominator (q = w*16+l15)

    const int r0 = tid >> 3;          // staging row 0..31
    const int c0 = (tid & 7) * 8;     // staging col

    // prefetch tile 0
    u16x8 rK0 = *(const u16x8*)&Kh[(size_t)r0 * DH + c0];
    u16x8 rK1 = *(const u16x8*)&Kh[(size_t)(r0 + 32) * DH + c0];
    u16x8 rV0 = *(const u16x8*)&Vth[(size_t)r0 * SEQ + c0];
    u16x8 rV1 = *(const u16x8*)&Vth[(size_t)(r0 + 32) * SEQ + c0];

    for (int kt = 0; kt <= qtB; kt++) {
        const int p = kt & 1;
        unsigned short* bKp = sK[p];
        unsigned short* bVp = sV[p];
        *(u16x8*)&bKp[r0 * 72 + c0]        = rK0;
        *(u16x8*)&bKp[(r0 + 32) * 72 + c0] = rK1;
        *(u16x8*)&bVp[r0 * 72 + c0]        = rV0;
        *(u16x8*)&bVp[(r0 + 32) * 72 + c0] = rV1;
        __syncthreads();

        if (kt < qtB) {
            const int k1 = (kt + 1) * 64;
            rK0 = *(const u16x8*)&Kh[(size_t)(k1 + r0) * DH + c0];
            rK1 = *(const u16x8*)&Kh[(size_t)(k1 + r0 + 32) * DH + c0];
            rV0 = *(const u16x8*)&Vth[(size_t)r0 * SEQ + k1 + c0];
            rV1 = *(const u16x8*)&Vth[(size_t)(r0 + 32) * SEQ + k1 + c0];
        }

        bf16x8 kf[8], vf[8];
#pragma unroll
        for (int ks = 0; ks < 2; ks++)
#pragma unroll
            for (int sub = 0; sub < 4; sub++) {
                kf[ks * 4 + sub] = *(const bf16x8*)
                    &bKp[(sub * 16 + l15) * 72 + ks * 32 + quad * 8];
                vf[ks * 4 + sub] = *(const bf16x8*)
                    &bVp[(sub * 16 + l15) * 72 + ks * 32 + quad * 8];
            }

        const bool doA = (kt <= qtA);

        // ---- S^T = K Q^T : D row = key-local (sub*16+quad*4+r), col = q-local l15
        f32x4 SB[4];
#pragma unroll
        for (int s = 0; s < 4; s++) SB[s] = (f32x4){0.f, 0.f, 0.f, 0.f};
#pragma unroll
        for (int ks = 0; ks < 2; ks++)
#pragma unroll
            for (int sub = 0; sub < 4; sub++)
                SB[sub] = __builtin_amdgcn_mfma_f32_16x16x32_bf16(
                    kf[ks * 4 + sub], qB[ks], SB[sub], 0, 0, 0);
        f32x4 SA[4];
        if (doA) {
#pragma unroll
            for (int s = 0; s < 4; s++) SA[s] = (f32x4){0.f, 0.f, 0.f, 0.f};
#pragma unroll
            for (int ks = 0; ks < 2; ks++)
#pragma unroll
                for (int sub = 0; sub < 4; sub++)
                    SA[sub] = __builtin_amdgcn_mfma_f32_16x16x32_bf16(
                        kf[ks * 4 + sub], qA[ks], SA[sub], 0, 0, 0);
        }

        // ---- softmax numerators (no max-sub), packed b64 P writes
        const bool diagB = (kt == qtB);
#pragma unroll
        for (int sub = 0; sub < 4; sub++) {
            ushort4 o;
            unsigned short* op = (unsigned short*)&o;
#pragma unroll
            for (int r = 0; r < 4; r++) {
                float pb = __expf(SB[sub][r]);
                if (diagB && (sub * 16 + quad * 4 + r > w * 16 + l15)) pb = 0.f;
                lBa += pb;
                op[r] = f2bf_fast(pb);
            }
            *(ushort4*)&sPB[(w * 16 + l15) * 72 + sub * 16 + quad * 4] = o;
        }
        if (doA) {
            const bool diagA = (kt == qtA);
#pragma unroll
            for (int sub = 0; sub < 4; sub++) {
                ushort4 o;
                unsigned short* op = (unsigned short*)&o;
#pragma unroll
                for (int r = 0; r < 4; r++) {
                    float pa = __expf(SA[sub][r]);
                    if (diagA && (sub * 16 + quad * 4 + r > w * 16 + l15)) pa = 0.f;
                    lAa += pa;
                    op[r] = f2bf_fast(pa);
                }
                *(ushort4*)&sPA[(w * 16 + l15) * 72 + sub * 16 + quad * 4] = o;
            }
        }
        __builtin_amdgcn_wave_barrier();

        // ---- O += V^T P^T : D row = e-local, col = q-local l15
#pragma unroll
        for (int ks = 0; ks < 2; ks++) {
            bf16x8 pb = *(const bf16x8*)
                &sPB[(w * 16 + l15) * 72 + ks * 32 + quad * 8];
#pragma unroll
            for (int sub = 0; sub < 4; sub++)
                OB[sub] = __builtin_amdgcn_mfma_f32_16x16x32_bf16(
                    vf[ks * 4 + sub], pb, OB[sub], 0, 0, 0);
        }
        if (doA) {
#pragma unroll
            for (int ks = 0; ks < 2; ks++) {
                bf16x8 pa = *(const bf16x8*)
                    &sPA[(w * 16 + l15) * 72 + ks * 32 + quad * 8];
#pragma unroll
                for (int sub = 0; sub < 4; sub++)
                    OA[sub] = __builtin_amdgcn_mfma_f32_16x16x32_bf16(
                        vf[ks * 4 + sub], pa, OA[sub], 0, 0, 0);
            }
        }
        __builtin_amdgcn_wave_barrier();
    }

    // ---- denominators: sum partials across the 4 quads (same l15)
    lAa += __shfl_xor(lAa, 16, 64);
    lAa += __shfl_xor(lAa, 32, 64);
    lBa += __shfl_xor(lBa, 16, 64);
    lBa += __shfl_xor(lBa, 32, 64);
    const float rlA = 1.0f / lAa;
    const float rlB = 1.0f / lBa;

    // ---- store: lane owns q = qt*64 + w*16 + l15, e = sub*16 + quad*4 + r
#pragma unroll
    for (int half = 0; half < 2; half++) {
        const int qt = half ? qtB : qtA;
        const f32x4* O4 = half ? OB : OA;
        const float rl = half ? rlB : rlA;
        const int q = qt * 64 + w * 16 + l15;
        unsigned short* zrow = Z + ((size_t)b * SEQ + q) * DM + h * DH;
#pragma unroll
        for (int sub = 0; sub < 4; sub++) {
            ushort4 o;
            unsigned short* op = (unsigned short*)&o;
#pragma unroll
            for (int r = 0; r < 4; r++) op[r] = f2bf(O4[sub][r] * rl);
            *(ushort4*)&zrow[sub * 16 + quad * 4] = o;
        }
    }
}

// ---------------------------------------------------------------------------
// out_mfma v2: pipelined ping-pong LDS, BK=32, one barrier/iter.
// Swapped operands -> coalesced float4 stores.
// ---------------------------------------------------------------------------
__global__ __launch_bounds__(256) void out_mfma(
    const unsigned short* __restrict__ Zb,
    const unsigned short* __restrict__ WOt,
    const float* __restrict__ bO,
    float* __restrict__ out)
{
    __shared__ __align__(16) unsigned short sA[2][64 * 40];
    __shared__ __align__(16) unsigned short sB[2][128 * 40];

    const int rowTile = blockIdx.x;
    const int colTile = blockIdx.y;
    const int rowBase = rowTile * 64;
    const int colBase = colTile * 128;

    const int tid  = threadIdx.x;
    const int w    = tid >> 6;
    const int lane = tid & 63;
    const int l15  = lane & 15;
    const int quad = lane >> 4;
    const int rw   = (w & 1) * 32;
    const int cw   = (w >> 1) * 64;

    f32x4 acc[2][4];
#pragma unroll
    for (int i = 0; i < 2; i++)
#pragma unroll
        for (int j = 0; j < 4; j++) acc[i][j] = (f32x4){0.f, 0.f, 0.f, 0.f};

    const int sr = tid >> 2;          // 0..63
    const int sc = (tid & 3) * 8;

    u16x8 rA0 = *(const u16x8*)&Zb[(size_t)(rowBase + sr) * DM + sc];
    u16x8 rB0 = *(const u16x8*)&WOt[(size_t)(colBase + sr) * DM + sc];
    u16x8 rB1 = *(const u16x8*)&WOt[(size_t)(colBase + sr + 64) * DM + sc];

    for (int kt = 0; kt < 32; kt++) {
        const int p = kt & 1;
        unsigned short* pA = sA[p];
        unsigned short* pB = sB[p];
        *(u16x8*)&pA[sr * 40 + sc]        = rA0;
        *(u16x8*)&pB[sr * 40 + sc]        = rB0;
        *(u16x8*)&pB[(sr + 64) * 40 + sc] = rB1;
        __syncthreads();

        if (kt < 31) {
            const int k1 = (kt + 1) * 32;
            rA0 = *(const u16x8*)&Zb[(size_t)(rowBase + sr) * DM + k1 + sc];
            rB0 = *(const u16x8*)&WOt[(size_t)(colBase + sr) * DM + k1 + sc];
            rB1 = *(const u16x8*)&WOt[(size_t)(colBase + sr + 64) * DM + k1 + sc];
        }

        bf16x8 af[2], bf[4];
#pragma unroll
        for (int i = 0; i < 2; i++)
            af[i] = *(const bf16x8*)&pA[(rw + i * 16 + l15) * 40 + quad * 8];
#pragma unroll
        for (int j = 0; j < 4; j++)
            bf[j] = *(const bf16x8*)&pB[(cw + j * 16 + l15) * 40 + quad * 8];
#pragma unroll
        for (int i = 0; i < 2; i++)
#pragma unroll
            for (int j = 0; j < 4; j++)
                acc[i][j] = __builtin_amdgcn_mfma_f32_16x16x32_bf16(
                    bf[j], af[i], acc[i][j], 0, 0, 0);
    }

#pragma unroll
    for (int i = 0; i < 2; i++) {
        int row = rowBase + rw + i * 16 + l15;
#pragma unroll
        for (int j = 0; j < 4; j++) {
            int col0 = colBase + cw + j * 16 + quad * 4;
            float4 o;
            o.x = acc[i][j][0] + bO[col0 + 0];
            o.y = acc[i][j][1] + bO[col0 + 1];
            o.z = acc[i][j][2] + bO[col0 + 2];
            o.w = acc[i][j][3] + bO[col0 + 3];
            *(float4*)&out[(size_t)row * DM + col0] = o;
        }
    }
}

// ---------------------------------------------------------------------------
extern "C" void kernel_launch(void* const* d_in, const int* in_sizes, int n_in,
                              void* d_out, int out_size, void* d_ws, size_t ws_size,
                              hipStream_t stream)
{
    const float* x  = (const float*)d_in[0];
    const float* WQ = (const float*)d_in[1];
    const float* WK = (const float*)d_in[2];
    const float* WV = (const float*)d_in[3];
    const float* WO = (const float*)d_in[4];
    const float* bQ = (const float*)d_in[5];
    const float* bK = (const float*)d_in[6];
    const float* bV = (const float*)d_in[7];
    const float* bO = (const float*)d_in[8];
    float* out = (float*)d_out;

    const size_t M4 = 4194304;
    unsigned short* xb  = (unsigned short*)d_ws;       // 4M (reused as Zb)
    unsigned short* Wt  = xb + M4;                     // 3M
    unsigned short* WOt = Wt + 3 * 1048576;            // 1M
    unsigned short* Qw  = WOt + 1048576;               // 4M
    unsigned short* Kw  = Qw + M4;                     // 4M
    unsigned short* Vtw = Kw + M4;                     // 4M (transposed V)
    unsigned short* Zb  = xb;

    conv_fused<<<3072, 256, 0, stream>>>(x, WQ, WK, WV, WO, xb, Wt, WOt);

    dim3 g1(32, 24);
    qkv_mfma<<<g1, 256, 0, stream>>>(xb, Wt, bQ, bK, bV, Qw, Kw, Vtw);

    attn_mfma<<<512, 256, 0, stream>>>(Qw, Kw, Vtw, Zb);

    dim3 g3(64, 8);
    out_mfma<<<g3, 256, 0, stream>>>(Zb, WOt, bO, out);
}

// Round 8
// 201.769 us; speedup vs baseline: 1.1602x; 1.0793x over previous
//
#include <hip/hip_runtime.h>
#include <math.h>

#define BATCH 2
#define SEQ   2048
#define NH    16
#define DH    64
#define DM    1024

typedef __attribute__((ext_vector_type(8))) short bf16x8;
typedef __attribute__((ext_vector_type(8))) unsigned short u16x8;
typedef __attribute__((ext_vector_type(4))) float f32x4;

__device__ __forceinline__ unsigned short f2bf(float f) {
    union { float f; unsigned u; } v; v.f = f;
    unsigned r = v.u + 0x7FFF + ((v.u >> 16) & 1);
    return (unsigned short)(r >> 16);
}
// cheap round-half-up (positive finite inputs; softmax weights)
__device__ __forceinline__ unsigned short f2bf_fast(float f) {
    union { float f; unsigned u; } v; v.f = f;
    return (unsigned short)((v.u + 0x8000u) >> 16);
}

// async global->LDS DMA, 16B per lane; LDS dst = wave-uniform base + lane*16
__device__ __forceinline__ void gl2lds16(const void* g, void* l) {
    __builtin_amdgcn_global_load_lds(
        (const __attribute__((address_space(1))) void*)g,
        (__attribute__((address_space(3))) void*)l,
        16, 0, 0);
}

// ---------------------------------------------------------------------------
// conv_fused: blockIdx < 2048 -> x fp32 -> bf16 ; else weight transposes.
// ---------------------------------------------------------------------------
__global__ __launch_bounds__(256) void conv_fused(
    const float* __restrict__ x,
    const float* __restrict__ WQ, const float* __restrict__ WK,
    const float* __restrict__ WV, const float* __restrict__ WO,
    unsigned short* __restrict__ xb,
    unsigned short* __restrict__ Wt, unsigned short* __restrict__ WOt)
{
    __shared__ float sT[64][68];
    const int tid = threadIdx.x;

    if (blockIdx.x < 2048) {
        size_t idx = ((size_t)blockIdx.x * 256 + tid) * 8;
        float4 a = *(const float4*)(x + idx);
        float4 b = *(const float4*)(x + idx + 4);
        u16x8 o;
        o[0] = f2bf(a.x); o[1] = f2bf(a.y); o[2] = f2bf(a.z); o[3] = f2bf(a.w);
        o[4] = f2bf(b.x); o[5] = f2bf(b.y); o[6] = f2bf(b.z); o[7] = f2bf(b.w);
        *(u16x8*)(xb + idx) = o;
        return;
    }
    const int t = blockIdx.x - 2048;
    if (t < 768) {
        int m = t >> 8, rem = t & 255, h = rem >> 4, dblk = rem & 15;
        const float* W = (m == 0) ? WQ : (m == 1) ? WK : WV;
        const float* in = W + (size_t)h * 65536 + dblk * 4096;
#pragma unroll
        for (int it = 0; it < 4; it++) {
            int idx = it * 1024 + tid * 4;
            int r = idx >> 6, c = idx & 63;
            *(float4*)(&sT[r][c]) = *(const float4*)(&in[(size_t)r * 64 + c]);
        }
        __syncthreads();
        unsigned short* out = Wt + (size_t)m * 1048576 + (size_t)h * 65536 + dblk * 64;
#pragma unroll
        for (int it = 0; it < 4; it++) {
            int idx = it * 1024 + tid * 4;
            int e = idx >> 6, d0 = idx & 63;
            ushort4 o;
            unsigned short* op = (unsigned short*)&o;
#pragma unroll
            for (int j = 0; j < 4; j++) op[j] = f2bf(sT[d0 + j][e]);
            *(ushort4*)&out[(size_t)e * 1024 + d0] = o;
        }
    } else {
        int tt = t - 768, rblk = tt >> 4, cblk = tt & 15;
        const float* in = WO + (size_t)rblk * 64 * 1024 + cblk * 64;
#pragma unroll
        for (int it = 0; it < 4; it++) {
            int idx = it * 1024 + tid * 4;
            int r = idx >> 6, c = idx & 63;
            *(float4*)(&sT[r][c]) = *(const float4*)(&in[(size_t)r * 1024 + c]);
        }
        __syncthreads();
        unsigned short* out = WOt + (size_t)cblk * 64 * 1024 + rblk * 64;
#pragma unroll
        for (int it = 0; it < 4; it++) {
            int idx = it * 1024 + tid * 4;
            int d = idx >> 6, he0 = idx & 63;
            ushort4 o;
            unsigned short* op = (unsigned short*)&o;
#pragma unroll
            for (int j = 0; j < 4; j++) op[j] = f2bf(sT[he0 + j][d]);
            *(ushort4*)&out[(size_t)d * 1024 + he0] = o;
        }
    }
}

// ---------------------------------------------------------------------------
// qkv_mfma v3: m97 structure — global_load_lds(16B) staging, unpadded [r][64]
// LDS with XOR chunk swizzle (chunk' = chunk ^ (row&7)) -> 2-way-only frag
// conflicts. BK=64, 2-barrier K-loop, single buffer.
// ---------------------------------------------------------------------------
__global__ __launch_bounds__(256) void qkv_mfma(
    const unsigned short* __restrict__ xb,
    const unsigned short* __restrict__ Wt,
    const float* __restrict__ bQ, const float* __restrict__ bK,
    const float* __restrict__ bV,
    unsigned short* __restrict__ Q, unsigned short* __restrict__ K,
    unsigned short* __restrict__ Vt)
{
    __shared__ __align__(16) unsigned short sA[128 * 64];
    __shared__ __align__(16) unsigned short sB[128 * 64];

    const int rowTile = blockIdx.x;
    const int m  = blockIdx.y >> 3;
    const int hp = blockIdx.y & 7;
    const unsigned short* Wm = Wt + (size_t)m * 1048576 + (size_t)hp * 2 * 65536;

    const int tid  = threadIdx.x;
    const int w    = tid >> 6;
    const int lane = tid & 63;
    const int l15  = lane & 15;
    const int quad = lane >> 4;
    const int rw   = (w & 1) * 64;
    const int cw   = (w >> 1) * 64;
    const int rowBase = rowTile * 128;

    // staging geometry: chunk = 1 KB = 8 rows x 64 cols; lane covers
    // row crow = lane>>3, source col chunk ccs = (lane&7) ^ (crow&7)
    const int crow = lane >> 3;
    const int ccs  = (((lane & 7) ^ crow) * 8);

    f32x4 acc[4][4];
#pragma unroll
    for (int i = 0; i < 4; i++)
#pragma unroll
        for (int j = 0; j < 4; j++) acc[i][j] = (f32x4){0.f, 0.f, 0.f, 0.f};

    for (int k0 = 0; k0 < DM; k0 += 64) {
        __syncthreads();   // previous tile's frag reads done
#pragma unroll
        for (int c = 0; c < 4; c++) {
            const int chunk = w * 4 + c;          // 0..15
            const int rr = chunk * 8 + crow;      // 0..127
            gl2lds16(&xb[(size_t)(rowBase + rr) * DM + k0 + ccs], &sA[chunk * 512]);
            gl2lds16(&Wm[(size_t)rr * DM + k0 + ccs],             &sB[chunk * 512]);
        }
        __syncthreads();   // vmcnt drained by compiler before barrier

#pragma unroll
        for (int ks = 0; ks < 2; ks++) {
            bf16x8 af[4], bf[4];
#pragma unroll
            for (int i = 0; i < 4; i++) {
                int ar = rw + i * 16 + l15;
                af[i] = *(const bf16x8*)&sA[ar * 64 + (((ks * 4 + quad) ^ (ar & 7)) * 8)];
            }
#pragma unroll
            for (int j = 0; j < 4; j++) {
                int br = cw + j * 16 + l15;
                bf[j] = *(const bf16x8*)&sB[br * 64 + (((ks * 4 + quad) ^ (br & 7)) * 8)];
            }
            if (m == 2) {
#pragma unroll
                for (int i = 0; i < 4; i++)
#pragma unroll
                    for (int j = 0; j < 4; j++)
                        acc[i][j] = __builtin_amdgcn_mfma_f32_16x16x32_bf16(
                            af[i], bf[j], acc[i][j], 0, 0, 0);
            } else {
#pragma unroll
                for (int i = 0; i < 4; i++)
#pragma unroll
                    for (int j = 0; j < 4; j++)
                        acc[i][j] = __builtin_amdgcn_mfma_f32_16x16x32_bf16(
                            bf[j], af[i], acc[i][j], 0, 0, 0);
            }
        }
    }

    if (m == 2) {
        // D[m=s][n=e]: lane holds fixed e, 4 consecutive s -> Vt[e][s] packed
#pragma unroll
        for (int j = 0; j < 4; j++) {
            int col = cw + j * 16 + l15;
            int h = hp * 2 + (col >> 6);
            int e = col & 63;
            float bv = bV[h * DH + e];
#pragma unroll
            for (int i = 0; i < 4; i++) {
                int row0 = rowBase + rw + i * 16 + quad * 4;
                int b = row0 >> 11, s0 = row0 & 2047;
                ushort4 o;
                unsigned short* op = (unsigned short*)&o;
#pragma unroll
                for (int r = 0; r < 4; r++) op[r] = f2bf(acc[i][j][r] + bv);
                *(ushort4*)&Vt[(((size_t)b * NH + h) * DH + e) * SEQ + s0] = o;
            }
        }
    } else {
        // D[m=e][n=s]: lane holds fixed s, 4 consecutive e -> [s][e] packed
        const float* bias = (m == 0) ? bQ : bK;
        unsigned short* Out = (m == 0) ? Q : K;
        const float scale = (m == 0) ? 0.125f : 1.0f;
#pragma unroll
        for (int i = 0; i < 4; i++) {
            int row = rowBase + rw + i * 16 + l15;
            int b = row >> 11, s = row & 2047;
#pragma unroll
            for (int j = 0; j < 4; j++) {
                int col0 = cw + j * 16 + quad * 4;
                int h = hp * 2 + (col0 >> 6);
                int e0 = col0 & 63;
                ushort4 o;
                unsigned short* op = (unsigned short*)&o;
#pragma unroll
                for (int r = 0; r < 4; r++)
                    op[r] = f2bf((acc[i][j][r] + bias[h * DH + e0 + r]) * scale);
                *(ushort4*)&Out[(((size_t)b * NH + h) * SEQ + s) * DH + e0] = o;
            }
        }
    }
}

// ---------------------------------------------------------------------------
// attn_mfma v6: same S^T math as v5; staging switched to global_load_lds with
// the XOR-swizzled unpadded [r][64] layout (identical pattern to qkv v3).
// ---------------------------------------------------------------------------
__global__ __launch_bounds__(256) void attn_mfma(
    const unsigned short* __restrict__ Q,    // [B][H][S][E] bf16, pre-scaled
    const unsigned short* __restrict__ K,    // [B][H][S][E] bf16
    const unsigned short* __restrict__ Vt,   // [B][H][E][S] bf16
    unsigned short* __restrict__ Z)          // [B][S][H*E] bf16
{
    __shared__ __align__(16) unsigned short sK [64 * 64];
    __shared__ __align__(16) unsigned short sV [64 * 64];
    __shared__ __align__(16) unsigned short sPA[64 * 72];
    __shared__ __align__(16) unsigned short sPB[64 * 72];

    const int h   = blockIdx.x & 15;
    const int b   = (blockIdx.x >> 4) & 1;
    const int i   = blockIdx.x >> 5;          // 0..15
    const int qtA = i;
    const int qtB = 31 - i;

    const int tid  = threadIdx.x;
    const int w    = tid >> 6;
    const int lane = tid & 63;
    const int l15  = lane & 15;
    const int quad = lane >> 4;

    const size_t headOff = ((size_t)b * NH + h) * SEQ * DH;
    const unsigned short* Qh  = Q  + headOff;
    const unsigned short* Kh  = K  + headOff;
    const unsigned short* Vth = Vt + headOff;   // [E][S]

    const unsigned short* qrowA =
        Qh + (size_t)(qtA * 64 + w * 16 + l15) * DH + quad * 8;
    const unsigned short* qrowB =
        Qh + (size_t)(qtB * 64 + w * 16 + l15) * DH + quad * 8;
    bf16x8 qA[2], qB[2];
    qA[0] = *(const bf16x8*)(qrowA);  qA[1] = *(const bf16x8*)(qrowA + 32);
    qB[0] = *(const bf16x8*)(qrowB);  qB[1] = *(const bf16x8*)(qrowB + 32);

    f32x4 OA[4], OB[4];
#pragma unroll
    for (int s = 0; s < 4; s++) {
        OA[s] = (f32x4){0.f, 0.f, 0.f, 0.f};
        OB[s] = (f32x4){0.f, 0.f, 0.f, 0.f};
    }
    float lAa = 0.f, lBa = 0.f;

    const int crow = lane >> 3;
    const int ccs  = (((lane & 7) ^ crow) * 8);

    for (int kt = 0; kt <= qtB; kt++) {
        const int k0 = kt * 64;
        __syncthreads();   // prev frag reads done
#pragma unroll
        for (int c = 0; c < 2; c++) {
            const int chunk = w * 2 + c;          // 0..7
            const int rr = chunk * 8 + crow;      // 0..63
            gl2lds16(&Kh[(size_t)(k0 + rr) * DH + ccs], &sK[chunk * 512]);
            gl2lds16(&Vth[(size_t)rr * SEQ + k0 + ccs], &sV[chunk * 512]);
        }
        __syncthreads();

        bf16x8 kf[8], vf[8];
#pragma unroll
        for (int ks = 0; ks < 2; ks++)
#pragma unroll
            for (int sub = 0; sub < 4; sub++) {
                int rr = sub * 16 + l15;
                int sw = ((ks * 4 + quad) ^ (rr & 7)) * 8;
                kf[ks * 4 + sub] = *(const bf16x8*)&sK[rr * 64 + sw];
                vf[ks * 4 + sub] = *(const bf16x8*)&sV[rr * 64 + sw];
            }

        const bool doA = (kt <= qtA);

        // ---- S^T = K Q^T
        f32x4 SB[4];
#pragma unroll
        for (int s = 0; s < 4; s++) SB[s] = (f32x4){0.f, 0.f, 0.f, 0.f};
#pragma unroll
        for (int ks = 0; ks < 2; ks++)
#pragma unroll
            for (int sub = 0; sub < 4; sub++)
                SB[sub] = __builtin_amdgcn_mfma_f32_16x16x32_bf16(
                    kf[ks * 4 + sub], qB[ks], SB[sub], 0, 0, 0);
        f32x4 SA[4];
        if (doA) {
#pragma unroll
            for (int s = 0; s < 4; s++) SA[s] = (f32x4){0.f, 0.f, 0.f, 0.f};
#pragma unroll
            for (int ks = 0; ks < 2; ks++)
#pragma unroll
                for (int sub = 0; sub < 4; sub++)
                    SA[sub] = __builtin_amdgcn_mfma_f32_16x16x32_bf16(
                        kf[ks * 4 + sub], qA[ks], SA[sub], 0, 0, 0);
        }

        // ---- softmax numerators (no max-sub), packed b64 P writes
        const bool diagB = (kt == qtB);
#pragma unroll
        for (int sub = 0; sub < 4; sub++) {
            ushort4 o;
            unsigned short* op = (unsigned short*)&o;
#pragma unroll
            for (int r = 0; r < 4; r++) {
                float pb = __expf(SB[sub][r]);
                if (diagB && (sub * 16 + quad * 4 + r > w * 16 + l15)) pb = 0.f;
                lBa += pb;
                op[r] = f2bf_fast(pb);
            }
            *(ushort4*)&sPB[(w * 16 + l15) * 72 + sub * 16 + quad * 4] = o;
        }
        if (doA) {
            const bool diagA = (kt == qtA);
#pragma unroll
            for (int sub = 0; sub < 4; sub++) {
                ushort4 o;
                unsigned short* op = (unsigned short*)&o;
#pragma unroll
                for (int r = 0; r < 4; r++) {
                    float pa = __expf(SA[sub][r]);
                    if (diagA && (sub * 16 + quad * 4 + r > w * 16 + l15)) pa = 0.f;
                    lAa += pa;
                    op[r] = f2bf_fast(pa);
                }
                *(ushort4*)&sPA[(w * 16 + l15) * 72 + sub * 16 + quad * 4] = o;
            }
        }
        __builtin_amdgcn_wave_barrier();

        // ---- O += V^T P^T
#pragma unroll
        for (int ks = 0; ks < 2; ks++) {
            bf16x8 pb = *(const bf16x8*)
                &sPB[(w * 16 + l15) * 72 + ks * 32 + quad * 8];
#pragma unroll
            for (int sub = 0; sub < 4; sub++)
                OB[sub] = __builtin_amdgcn_mfma_f32_16x16x32_bf16(
                    vf[ks * 4 + sub], pb, OB[sub], 0, 0, 0);
        }
        if (doA) {
#pragma unroll
            for (int ks = 0; ks < 2; ks++) {
                bf16x8 pa = *(const bf16x8*)
                    &sPA[(w * 16 + l15) * 72 + ks * 32 + quad * 8];
#pragma unroll
                for (int sub = 0; sub < 4; sub++)
                    OA[sub] = __builtin_amdgcn_mfma_f32_16x16x32_bf16(
                        vf[ks * 4 + sub], pa, OA[sub], 0, 0, 0);
            }
        }
        __builtin_amdgcn_wave_barrier();
    }

    // ---- denominators: sum partials across the 4 quads (same l15)
    lAa += __shfl_xor(lAa, 16, 64);
    lAa += __shfl_xor(lAa, 32, 64);
    lBa += __shfl_xor(lBa, 16, 64);
    lBa += __shfl_xor(lBa, 32, 64);
    const float rlA = 1.0f / lAa;
    const float rlB = 1.0f / lBa;

    // ---- store: lane owns q = qt*64 + w*16 + l15, e = sub*16 + quad*4 + r
#pragma unroll
    for (int half = 0; half < 2; half++) {
        const int qt = half ? qtB : qtA;
        const f32x4* O4 = half ? OB : OA;
        const float rl = half ? rlB : rlA;
        const int q = qt * 64 + w * 16 + l15;
        unsigned short* zrow = Z + ((size_t)b * SEQ + q) * DM + h * DH;
#pragma unroll
        for (int sub = 0; sub < 4; sub++) {
            ushort4 o;
            unsigned short* op = (unsigned short*)&o;
#pragma unroll
            for (int r = 0; r < 4; r++) op[r] = f2bf(O4[sub][r] * rl);
            *(ushort4*)&zrow[sub * 16 + quad * 4] = o;
        }
    }
}

// ---------------------------------------------------------------------------
// out_mfma v3: m97 structure, 64x128 tile, global_load_lds + XOR swizzle.
// ---------------------------------------------------------------------------
__global__ __launch_bounds__(256) void out_mfma(
    const unsigned short* __restrict__ Zb,
    const unsigned short* __restrict__ WOt,
    const float* __restrict__ bO,
    float* __restrict__ out)
{
    __shared__ __align__(16) unsigned short sA[64 * 64];
    __shared__ __align__(16) unsigned short sB[128 * 64];

    const int rowTile = blockIdx.x;
    const int colTile = blockIdx.y;
    const int rowBase = rowTile * 64;
    const int colBase = colTile * 128;

    const int tid  = threadIdx.x;
    const int w    = tid >> 6;
    const int lane = tid & 63;
    const int l15  = lane & 15;
    const int quad = lane >> 4;
    const int rw   = (w & 1) * 32;
    const int cw   = (w >> 1) * 64;

    const int crow = lane >> 3;
    const int ccs  = (((lane & 7) ^ crow) * 8);

    f32x4 acc[2][4];
#pragma unroll
    for (int i = 0; i < 2; i++)
#pragma unroll
        for (int j = 0; j < 4; j++) acc[i][j] = (f32x4){0.f, 0.f, 0.f, 0.f};

    for (int k0 = 0; k0 < DM; k0 += 64) {
        __syncthreads();
#pragma unroll
        for (int c = 0; c < 2; c++) {
            const int chunk = w * 2 + c;          // 0..7
            const int rr = chunk * 8 + crow;      // 0..63
            gl2lds16(&Zb[(size_t)(rowBase + rr) * DM + k0 + ccs], &sA[chunk * 512]);
        }
#pragma unroll
        for (int c = 0; c < 4; c++) {
            const int chunk = w * 4 + c;          // 0..15
            const int rr = chunk * 8 + crow;      // 0..127
            gl2lds16(&WOt[(size_t)(colBase + rr) * DM + k0 + ccs], &sB[chunk * 512]);
        }
        __syncthreads();

#pragma unroll
        for (int ks = 0; ks < 2; ks++) {
            bf16x8 af[2], bf[4];
#pragma unroll
            for (int i = 0; i < 2; i++) {
                int ar = rw + i * 16 + l15;
                af[i] = *(const bf16x8*)&sA[ar * 64 + (((ks * 4 + quad) ^ (ar & 7)) * 8)];
            }
#pragma unroll
            for (int j = 0; j < 4; j++) {
                int br = cw + j * 16 + l15;
                bf[j] = *(const bf16x8*)&sB[br * 64 + (((ks * 4 + quad) ^ (br & 7)) * 8)];
            }
#pragma unroll
            for (int i = 0; i < 2; i++)
#pragma unroll
                for (int j = 0; j < 4; j++)
                    acc[i][j] = __builtin_amdgcn_mfma_f32_16x16x32_bf16(
                        bf[j], af[i], acc[i][j], 0, 0, 0);
        }
    }

#pragma unroll
    for (int i = 0; i < 2; i++) {
        int row = rowBase + rw + i * 16 + l15;
#pragma unroll
        for (int j = 0; j < 4; j++) {
            int col0 = colBase + cw + j * 16 + quad * 4;
            float4 o;
            o.x = acc[i][j][0] + bO[col0 + 0];
            o.y = acc[i][j][1] + bO[col0 + 1];
            o.z = acc[i][j][2] + bO[col0 + 2];
            o.w = acc[i][j][3] + bO[col0 + 3];
            *(float4*)&out[(size_t)row * DM + col0] = o;
        }
    }
}

// ---------------------------------------------------------------------------
extern "C" void kernel_launch(void* const* d_in, const int* in_sizes, int n_in,
                              void* d_out, int out_size, void* d_ws, size_t ws_size,
                              hipStream_t stream)
{
    const float* x  = (const float*)d_in[0];
    const float* WQ = (const float*)d_in[1];
    const float* WK = (const float*)d_in[2];
    const float* WV = (const float*)d_in[3];
    const float* WO = (const float*)d_in[4];
    const float* bQ = (const float*)d_in[5];
    const float* bK = (const float*)d_in[6];
    const float* bV = (const float*)d_in[7];
    const float* bO = (const float*)d_in[8];
    float* out = (float*)d_out;

    const size_t M4 = 4194304;
    unsigned short* xb  = (unsigned short*)d_ws;       // 4M (reused as Zb)
    unsigned short* Wt  = xb + M4;                     // 3M
    unsigned short* WOt = Wt + 3 * 1048576;            // 1M
    unsigned short* Qw  = WOt + 1048576;               // 4M
    unsigned short* Kw  = Qw + M4;                     // 4M
    unsigned short* Vtw = Kw + M4;                     // 4M (transposed V)
    unsigned short* Zb  = xb;

    conv_fused<<<3072, 256, 0, stream>>>(x, WQ, WK, WV, WO, xb, Wt, WOt);

    dim3 g1(32, 24);
    qkv_mfma<<<g1, 256, 0, stream>>>(xb, Wt, bQ, bK, bV, Qw, Kw, Vtw);

    attn_mfma<<<512, 256, 0, stream>>>(Qw, Kw, Vtw, Zb);

    dim3 g3(64, 8);
    out_mfma<<<g3, 256, 0, stream>>>(Zb, WOt, bO, out);
}

// Round 9
// 186.087 us; speedup vs baseline: 1.2580x; 1.0843x over previous
//
#include <hip/hip_runtime.h>
#include <math.h>

#define BATCH 2
#define SEQ   2048
#define NH    16
#define DH    64
#define DM    1024

typedef __attribute__((ext_vector_type(8))) short bf16x8;
typedef __attribute__((ext_vector_type(8))) unsigned short u16x8;
typedef __attribute__((ext_vector_type(4))) float f32x4;

__device__ __forceinline__ unsigned short f2bf(float f) {
    union { float f; unsigned u; } v; v.f = f;
    unsigned r = v.u + 0x7FFF + ((v.u >> 16) & 1);
    return (unsigned short)(r >> 16);
}
// cheap round-half-up (positive finite inputs; softmax weights)
__device__ __forceinline__ unsigned short f2bf_fast(float f) {
    union { float f; unsigned u; } v; v.f = f;
    return (unsigned short)((v.u + 0x8000u) >> 16);
}

// async global->LDS DMA, 16B per lane; LDS dst = wave-uniform base + lane*16
__device__ __forceinline__ void gl2lds16(const void* g, void* l) {
    __builtin_amdgcn_global_load_lds(
        (const __attribute__((address_space(1))) void*)g,
        (__attribute__((address_space(3))) void*)l,
        16, 0, 0);
}

// ---------------------------------------------------------------------------
// conv_fused: blockIdx < 2048 -> x fp32 -> bf16 ; else weight transposes.
// ---------------------------------------------------------------------------
__global__ __launch_bounds__(256) void conv_fused(
    const float* __restrict__ x,
    const float* __restrict__ WQ, const float* __restrict__ WK,
    const float* __restrict__ WV, const float* __restrict__ WO,
    unsigned short* __restrict__ xb,
    unsigned short* __restrict__ Wt, unsigned short* __restrict__ WOt)
{
    __shared__ float sT[64][68];
    const int tid = threadIdx.x;

    if (blockIdx.x < 2048) {
        size_t idx = ((size_t)blockIdx.x * 256 + tid) * 8;
        float4 a = *(const float4*)(x + idx);
        float4 b = *(const float4*)(x + idx + 4);
        u16x8 o;
        o[0] = f2bf(a.x); o[1] = f2bf(a.y); o[2] = f2bf(a.z); o[3] = f2bf(a.w);
        o[4] = f2bf(b.x); o[5] = f2bf(b.y); o[6] = f2bf(b.z); o[7] = f2bf(b.w);
        *(u16x8*)(xb + idx) = o;
        return;
    }
    const int t = blockIdx.x - 2048;
    if (t < 768) {
        int m = t >> 8, rem = t & 255, h = rem >> 4, dblk = rem & 15;
        const float* W = (m == 0) ? WQ : (m == 1) ? WK : WV;
        const float* in = W + (size_t)h * 65536 + dblk * 4096;
#pragma unroll
        for (int it = 0; it < 4; it++) {
            int idx = it * 1024 + tid * 4;
            int r = idx >> 6, c = idx & 63;
            *(float4*)(&sT[r][c]) = *(const float4*)(&in[(size_t)r * 64 + c]);
        }
        __syncthreads();
        unsigned short* out = Wt + (size_t)m * 1048576 + (size_t)h * 65536 + dblk * 64;
#pragma unroll
        for (int it = 0; it < 4; it++) {
            int idx = it * 1024 + tid * 4;
            int e = idx >> 6, d0 = idx & 63;
            ushort4 o;
            unsigned short* op = (unsigned short*)&o;
#pragma unroll
            for (int j = 0; j < 4; j++) op[j] = f2bf(sT[d0 + j][e]);
            *(ushort4*)&out[(size_t)e * 1024 + d0] = o;
        }
    } else {
        int tt = t - 768, rblk = tt >> 4, cblk = tt & 15;
        const float* in = WO + (size_t)rblk * 64 * 1024 + cblk * 64;
#pragma unroll
        for (int it = 0; it < 4; it++) {
            int idx = it * 1024 + tid * 4;
            int r = idx >> 6, c = idx & 63;
            *(float4*)(&sT[r][c]) = *(const float4*)(&in[(size_t)r * 1024 + c]);
        }
        __syncthreads();
        unsigned short* out = WOt + (size_t)cblk * 64 * 1024 + rblk * 64;
#pragma unroll
        for (int it = 0; it < 4; it++) {
            int idx = it * 1024 + tid * 4;
            int d = idx >> 6, he0 = idx & 63;
            ushort4 o;
            unsigned short* op = (unsigned short*)&o;
#pragma unroll
            for (int j = 0; j < 4; j++) op[j] = f2bf(sT[he0 + j][d]);
            *(ushort4*)&out[(size_t)d * 1024 + he0] = o;
        }
    }
}

// ---------------------------------------------------------------------------
// qkv_mfma v4: async-prefetch LDS double-buffer, ONE barrier/iter.
//   barrier(kt) => DMA(kt) landed (per-wave vmcnt drain + join) AND the
//   buffer DMA(kt+1) overwrites is no longer being read.
// XOR chunk swizzle keeps frag reads conflict-free (r8: conflicts == 0).
// ---------------------------------------------------------------------------
__global__ __launch_bounds__(256) void qkv_mfma(
    const unsigned short* __restrict__ xb,
    const unsigned short* __restrict__ Wt,
    const float* __restrict__ bQ, const float* __restrict__ bK,
    const float* __restrict__ bV,
    unsigned short* __restrict__ Q, unsigned short* __restrict__ K,
    unsigned short* __restrict__ Vt)
{
    __shared__ __align__(16) unsigned short sA[2][128 * 64];
    __shared__ __align__(16) unsigned short sB[2][128 * 64];

    const int rowTile = blockIdx.x;
    const int m  = blockIdx.y >> 3;
    const int hp = blockIdx.y & 7;
    const unsigned short* Wm = Wt + (size_t)m * 1048576 + (size_t)hp * 2 * 65536;

    const int tid  = threadIdx.x;
    const int w    = tid >> 6;
    const int lane = tid & 63;
    const int l15  = lane & 15;
    const int quad = lane >> 4;
    const int rw   = (w & 1) * 64;
    const int cw   = (w >> 1) * 64;
    const int rowBase = rowTile * 128;

    const int crow = lane >> 3;
    const int ccs  = (((lane & 7) ^ crow) * 8);

    f32x4 acc[4][4];
#pragma unroll
    for (int i = 0; i < 4; i++)
#pragma unroll
        for (int j = 0; j < 4; j++) acc[i][j] = (f32x4){0.f, 0.f, 0.f, 0.f};

    // prologue: stage tile 0 into buffer 0
#pragma unroll
    for (int c = 0; c < 4; c++) {
        const int chunk = w * 4 + c;
        const int rr = chunk * 8 + crow;
        gl2lds16(&xb[(size_t)(rowBase + rr) * DM + ccs], &sA[0][chunk * 512]);
        gl2lds16(&Wm[(size_t)rr * DM + ccs],             &sB[0][chunk * 512]);
    }

    for (int kt = 0; kt < 16; kt++) {
        __syncthreads();   // DMA(kt) landed; buf(kt+1&1) free for overwrite
        if (kt < 15) {
            const int k1 = (kt + 1) * 64;
            unsigned short* dA = sA[(kt + 1) & 1];
            unsigned short* dB = sB[(kt + 1) & 1];
#pragma unroll
            for (int c = 0; c < 4; c++) {
                const int chunk = w * 4 + c;
                const int rr = chunk * 8 + crow;
                gl2lds16(&xb[(size_t)(rowBase + rr) * DM + k1 + ccs], &dA[chunk * 512]);
                gl2lds16(&Wm[(size_t)rr * DM + k1 + ccs],             &dB[chunk * 512]);
            }
        }
        const unsigned short* pA = sA[kt & 1];
        const unsigned short* pB = sB[kt & 1];

#pragma unroll
        for (int ks = 0; ks < 2; ks++) {
            bf16x8 af[4], bf[4];
#pragma unroll
            for (int i = 0; i < 4; i++) {
                int ar = rw + i * 16 + l15;
                af[i] = *(const bf16x8*)&pA[ar * 64 + (((ks * 4 + quad) ^ (ar & 7)) * 8)];
            }
#pragma unroll
            for (int j = 0; j < 4; j++) {
                int br = cw + j * 16 + l15;
                bf[j] = *(const bf16x8*)&pB[br * 64 + (((ks * 4 + quad) ^ (br & 7)) * 8)];
            }
            if (m == 2) {
#pragma unroll
                for (int i = 0; i < 4; i++)
#pragma unroll
                    for (int j = 0; j < 4; j++)
                        acc[i][j] = __builtin_amdgcn_mfma_f32_16x16x32_bf16(
                            af[i], bf[j], acc[i][j], 0, 0, 0);
            } else {
#pragma unroll
                for (int i = 0; i < 4; i++)
#pragma unroll
                    for (int j = 0; j < 4; j++)
                        acc[i][j] = __builtin_amdgcn_mfma_f32_16x16x32_bf16(
                            bf[j], af[i], acc[i][j], 0, 0, 0);
            }
        }
    }

    if (m == 2) {
        // D[m=s][n=e]: lane holds fixed e, 4 consecutive s -> Vt[e][s] packed
#pragma unroll
        for (int j = 0; j < 4; j++) {
            int col = cw + j * 16 + l15;
            int h = hp * 2 + (col >> 6);
            int e = col & 63;
            float bv = bV[h * DH + e];
#pragma unroll
            for (int i = 0; i < 4; i++) {
                int row0 = rowBase + rw + i * 16 + quad * 4;
                int b = row0 >> 11, s0 = row0 & 2047;
                ushort4 o;
                unsigned short* op = (unsigned short*)&o;
#pragma unroll
                for (int r = 0; r < 4; r++) op[r] = f2bf(acc[i][j][r] + bv);
                *(ushort4*)&Vt[(((size_t)b * NH + h) * DH + e) * SEQ + s0] = o;
            }
        }
    } else {
        // D[m=e][n=s]: lane holds fixed s, 4 consecutive e -> [s][e] packed
        const float* bias = (m == 0) ? bQ : bK;
        unsigned short* Out = (m == 0) ? Q : K;
        const float scale = (m == 0) ? 0.125f : 1.0f;
        float4 bb[4];
        int hj[4], e0j[4];
#pragma unroll
        for (int j = 0; j < 4; j++) {
            int col0 = cw + j * 16 + quad * 4;
            hj[j] = hp * 2 + (col0 >> 6);
            e0j[j] = col0 & 63;
            bb[j] = *(const float4*)&bias[hj[j] * DH + e0j[j]];
        }
#pragma unroll
        for (int i = 0; i < 4; i++) {
            int row = rowBase + rw + i * 16 + l15;
            int b = row >> 11, s = row & 2047;
#pragma unroll
            for (int j = 0; j < 4; j++) {
                const float* bp = (const float*)&bb[j];
                ushort4 o;
                unsigned short* op = (unsigned short*)&o;
#pragma unroll
                for (int r = 0; r < 4; r++)
                    op[r] = f2bf((acc[i][j][r] + bp[r]) * scale);
                *(ushort4*)&Out[(((size_t)b * NH + hj[j]) * SEQ + s) * DH + e0j[j]] = o;
            }
        }
    }
}

// ---------------------------------------------------------------------------
// attn_mfma v7: v6 + async-prefetch LDS double-buffer (one __syncthreads/iter).
// ---------------------------------------------------------------------------
__global__ __launch_bounds__(256) void attn_mfma(
    const unsigned short* __restrict__ Q,    // [B][H][S][E] bf16, pre-scaled
    const unsigned short* __restrict__ K,    // [B][H][S][E] bf16
    const unsigned short* __restrict__ Vt,   // [B][H][E][S] bf16
    unsigned short* __restrict__ Z)          // [B][S][H*E] bf16
{
    __shared__ __align__(16) unsigned short sK [2][64 * 64];
    __shared__ __align__(16) unsigned short sV [2][64 * 64];
    __shared__ __align__(16) unsigned short sPA[64 * 72];
    __shared__ __align__(16) unsigned short sPB[64 * 72];

    const int h   = blockIdx.x & 15;
    const int b   = (blockIdx.x >> 4) & 1;
    const int i   = blockIdx.x >> 5;          // 0..15
    const int qtA = i;
    const int qtB = 31 - i;

    const int tid  = threadIdx.x;
    const int w    = tid >> 6;
    const int lane = tid & 63;
    const int l15  = lane & 15;
    const int quad = lane >> 4;

    const size_t headOff = ((size_t)b * NH + h) * SEQ * DH;
    const unsigned short* Qh  = Q  + headOff;
    const unsigned short* Kh  = K  + headOff;
    const unsigned short* Vth = Vt + headOff;   // [E][S]

    const unsigned short* qrowA =
        Qh + (size_t)(qtA * 64 + w * 16 + l15) * DH + quad * 8;
    const unsigned short* qrowB =
        Qh + (size_t)(qtB * 64 + w * 16 + l15) * DH + quad * 8;
    bf16x8 qA[2], qB[2];
    qA[0] = *(const bf16x8*)(qrowA);  qA[1] = *(const bf16x8*)(qrowA + 32);
    qB[0] = *(const bf16x8*)(qrowB);  qB[1] = *(const bf16x8*)(qrowB + 32);

    f32x4 OA[4], OB[4];
#pragma unroll
    for (int s = 0; s < 4; s++) {
        OA[s] = (f32x4){0.f, 0.f, 0.f, 0.f};
        OB[s] = (f32x4){0.f, 0.f, 0.f, 0.f};
    }
    float lAa = 0.f, lBa = 0.f;

    const int crow = lane >> 3;
    const int ccs  = (((lane & 7) ^ crow) * 8);

    // prologue: stage tile 0 into buffer 0
#pragma unroll
    for (int c = 0; c < 2; c++) {
        const int chunk = w * 2 + c;
        const int rr = chunk * 8 + crow;
        gl2lds16(&Kh[(size_t)rr * DH + ccs],  &sK[0][chunk * 512]);
        gl2lds16(&Vth[(size_t)rr * SEQ + ccs], &sV[0][chunk * 512]);
    }

    for (int kt = 0; kt <= qtB; kt++) {
        __syncthreads();   // DMA(kt) landed; other buffer free
        if (kt < qtB) {
            const int k1 = (kt + 1) * 64;
            unsigned short* dK = sK[(kt + 1) & 1];
            unsigned short* dV = sV[(kt + 1) & 1];
#pragma unroll
            for (int c = 0; c < 2; c++) {
                const int chunk = w * 2 + c;
                const int rr = chunk * 8 + crow;
                gl2lds16(&Kh[(size_t)(k1 + rr) * DH + ccs], &dK[chunk * 512]);
                gl2lds16(&Vth[(size_t)rr * SEQ + k1 + ccs], &dV[chunk * 512]);
            }
        }
        const unsigned short* pK = sK[kt & 1];
        const unsigned short* pV = sV[kt & 1];

        bf16x8 kf[8], vf[8];
#pragma unroll
        for (int ks = 0; ks < 2; ks++)
#pragma unroll
            for (int sub = 0; sub < 4; sub++) {
                int rr = sub * 16 + l15;
                int sw = ((ks * 4 + quad) ^ (rr & 7)) * 8;
                kf[ks * 4 + sub] = *(const bf16x8*)&pK[rr * 64 + sw];
                vf[ks * 4 + sub] = *(const bf16x8*)&pV[rr * 64 + sw];
            }

        const bool doA = (kt <= qtA);

        // ---- S^T = K Q^T
        f32x4 SB[4];
#pragma unroll
        for (int s = 0; s < 4; s++) SB[s] = (f32x4){0.f, 0.f, 0.f, 0.f};
#pragma unroll
        for (int ks = 0; ks < 2; ks++)
#pragma unroll
            for (int sub = 0; sub < 4; sub++)
                SB[sub] = __builtin_amdgcn_mfma_f32_16x16x32_bf16(
                    kf[ks * 4 + sub], qB[ks], SB[sub], 0, 0, 0);
        f32x4 SA[4];
        if (doA) {
#pragma unroll
            for (int s = 0; s < 4; s++) SA[s] = (f32x4){0.f, 0.f, 0.f, 0.f};
#pragma unroll
            for (int ks = 0; ks < 2; ks++)
#pragma unroll
                for (int sub = 0; sub < 4; sub++)
                    SA[sub] = __builtin_amdgcn_mfma_f32_16x16x32_bf16(
                        kf[ks * 4 + sub], qA[ks], SA[sub], 0, 0, 0);
        }

        // ---- softmax numerators (no max-sub), packed b64 P writes
        const bool diagB = (kt == qtB);
#pragma unroll
        for (int sub = 0; sub < 4; sub++) {
            ushort4 o;
            unsigned short* op = (unsigned short*)&o;
#pragma unroll
            for (int r = 0; r < 4; r++) {
                float pb = __expf(SB[sub][r]);
                if (diagB && (sub * 16 + quad * 4 + r > w * 16 + l15)) pb = 0.f;
                lBa += pb;
                op[r] = f2bf_fast(pb);
            }
            *(ushort4*)&sPB[(w * 16 + l15) * 72 + sub * 16 + quad * 4] = o;
        }
        if (doA) {
            const bool diagA = (kt == qtA);
#pragma unroll
            for (int sub = 0; sub < 4; sub++) {
                ushort4 o;
                unsigned short* op = (unsigned short*)&o;
#pragma unroll
                for (int r = 0; r < 4; r++) {
                    float pa = __expf(SA[sub][r]);
                    if (diagA && (sub * 16 + quad * 4 + r > w * 16 + l15)) pa = 0.f;
                    lAa += pa;
                    op[r] = f2bf_fast(pa);
                }
                *(ushort4*)&sPA[(w * 16 + l15) * 72 + sub * 16 + quad * 4] = o;
            }
        }
        __builtin_amdgcn_wave_barrier();

        // ---- O += V^T P^T
#pragma unroll
        for (int ks = 0; ks < 2; ks++) {
            bf16x8 pb = *(const bf16x8*)
                &sPB[(w * 16 + l15) * 72 + ks * 32 + quad * 8];
#pragma unroll
            for (int sub = 0; sub < 4; sub++)
                OB[sub] = __builtin_amdgcn_mfma_f32_16x16x32_bf16(
                    vf[ks * 4 + sub], pb, OB[sub], 0, 0, 0);
        }
        if (doA) {
#pragma unroll
            for (int ks = 0; ks < 2; ks++) {
                bf16x8 pa = *(const bf16x8*)
                    &sPA[(w * 16 + l15) * 72 + ks * 32 + quad * 8];
#pragma unroll
                for (int sub = 0; sub < 4; sub++)
                    OA[sub] = __builtin_amdgcn_mfma_f32_16x16x32_bf16(
                        vf[ks * 4 + sub], pa, OA[sub], 0, 0, 0);
            }
        }
        __builtin_amdgcn_wave_barrier();
    }

    // ---- denominators: sum partials across the 4 quads (same l15)
    lAa += __shfl_xor(lAa, 16, 64);
    lAa += __shfl_xor(lAa, 32, 64);
    lBa += __shfl_xor(lBa, 16, 64);
    lBa += __shfl_xor(lBa, 32, 64);
    const float rlA = 1.0f / lAa;
    const float rlB = 1.0f / lBa;

    // ---- store: lane owns q = qt*64 + w*16 + l15, e = sub*16 + quad*4 + r
#pragma unroll
    for (int half = 0; half < 2; half++) {
        const int qt = half ? qtB : qtA;
        const f32x4* O4 = half ? OB : OA;
        const float rl = half ? rlB : rlA;
        const int q = qt * 64 + w * 16 + l15;
        unsigned short* zrow = Z + ((size_t)b * SEQ + q) * DM + h * DH;
#pragma unroll
        for (int sub = 0; sub < 4; sub++) {
            ushort4 o;
            unsigned short* op = (unsigned short*)&o;
#pragma unroll
            for (int r = 0; r < 4; r++) op[r] = f2bf(O4[sub][r] * rl);
            *(ushort4*)&zrow[sub * 16 + quad * 4] = o;
        }
    }
}

// ---------------------------------------------------------------------------
// out_mfma v4: async-prefetch LDS double-buffer, one barrier/iter.
// ---------------------------------------------------------------------------
__global__ __launch_bounds__(256) void out_mfma(
    const unsigned short* __restrict__ Zb,
    const unsigned short* __restrict__ WOt,
    const float* __restrict__ bO,
    float* __restrict__ out)
{
    __shared__ __align__(16) unsigned short sA[2][64 * 64];
    __shared__ __align__(16) unsigned short sB[2][128 * 64];

    const int rowTile = blockIdx.x;
    const int colTile = blockIdx.y;
    const int rowBase = rowTile * 64;
    const int colBase = colTile * 128;

    const int tid  = threadIdx.x;
    const int w    = tid >> 6;
    const int lane = tid & 63;
    const int l15  = lane & 15;
    const int quad = lane >> 4;
    const int rw   = (w & 1) * 32;
    const int cw   = (w >> 1) * 64;

    const int crow = lane >> 3;
    const int ccs  = (((lane & 7) ^ crow) * 8);

    f32x4 acc[2][4];
#pragma unroll
    for (int i = 0; i < 2; i++)
#pragma unroll
        for (int j = 0; j < 4; j++) acc[i][j] = (f32x4){0.f, 0.f, 0.f, 0.f};

    // prologue: stage tile 0
#pragma unroll
    for (int c = 0; c < 2; c++) {
        const int chunk = w * 2 + c;
        const int rr = chunk * 8 + crow;
        gl2lds16(&Zb[(size_t)(rowBase + rr) * DM + ccs], &sA[0][chunk * 512]);
    }
#pragma unroll
    for (int c = 0; c < 4; c++) {
        const int chunk = w * 4 + c;
        const int rr = chunk * 8 + crow;
        gl2lds16(&WOt[(size_t)(colBase + rr) * DM + ccs], &sB[0][chunk * 512]);
    }

    for (int kt = 0; kt < 16; kt++) {
        __syncthreads();
        if (kt < 15) {
            const int k1 = (kt + 1) * 64;
            unsigned short* dA = sA[(kt + 1) & 1];
            unsigned short* dB = sB[(kt + 1) & 1];
#pragma unroll
            for (int c = 0; c < 2; c++) {
                const int chunk = w * 2 + c;
                const int rr = chunk * 8 + crow;
                gl2lds16(&Zb[(size_t)(rowBase + rr) * DM + k1 + ccs], &dA[chunk * 512]);
            }
#pragma unroll
            for (int c = 0; c < 4; c++) {
                const int chunk = w * 4 + c;
                const int rr = chunk * 8 + crow;
                gl2lds16(&WOt[(size_t)(colBase + rr) * DM + k1 + ccs], &dB[chunk * 512]);
            }
        }
        const unsigned short* pA = sA[kt & 1];
        const unsigned short* pB = sB[kt & 1];

#pragma unroll
        for (int ks = 0; ks < 2; ks++) {
            bf16x8 af[2], bf[4];
#pragma unroll
            for (int i = 0; i < 2; i++) {
                int ar = rw + i * 16 + l15;
                af[i] = *(const bf16x8*)&pA[ar * 64 + (((ks * 4 + quad) ^ (ar & 7)) * 8)];
            }
#pragma unroll
            for (int j = 0; j < 4; j++) {
                int br = cw + j * 16 + l15;
                bf[j] = *(const bf16x8*)&pB[br * 64 + (((ks * 4 + quad) ^ (br & 7)) * 8)];
            }
#pragma unroll
            for (int i = 0; i < 2; i++)
#pragma unroll
                for (int j = 0; j < 4; j++)
                    acc[i][j] = __builtin_amdgcn_mfma_f32_16x16x32_bf16(
                        bf[j], af[i], acc[i][j], 0, 0, 0);
        }
    }

#pragma unroll
    for (int i = 0; i < 2; i++) {
        int row = rowBase + rw + i * 16 + l15;
#pragma unroll
        for (int j = 0; j < 4; j++) {
            int col0 = colBase + cw + j * 16 + quad * 4;
            float4 o;
            o.x = acc[i][j][0] + bO[col0 + 0];
            o.y = acc[i][j][1] + bO[col0 + 1];
            o.z = acc[i][j][2] + bO[col0 + 2];
            o.w = acc[i][j][3] + bO[col0 + 3];
            *(float4*)&out[(size_t)row * DM + col0] = o;
        }
    }
}

// ---------------------------------------------------------------------------
extern "C" void kernel_launch(void* const* d_in, const int* in_sizes, int n_in,
                              void* d_out, int out_size, void* d_ws, size_t ws_size,
                              hipStream_t stream)
{
    const float* x  = (const float*)d_in[0];
    const float* WQ = (const float*)d_in[1];
    const float* WK = (const float*)d_in[2];
    const float* WV = (const float*)d_in[3];
    const float* WO = (const float*)d_in[4];
    const float* bQ = (const float*)d_in[5];
    const float* bK = (const float*)d_in[6];
    const float* bV = (const float*)d_in[7];
    const float* bO = (const float*)d_in[8];
    float* out = (float*)d_out;

    const size_t M4 = 4194304;
    unsigned short* xb  = (unsigned short*)d_ws;       // 4M (reused as Zb)
    unsigned short* Wt  = xb + M4;                     // 3M
    unsigned short* WOt = Wt + 3 * 1048576;            // 1M
    unsigned short* Qw  = WOt + 1048576;               // 4M
    unsigned short* Kw  = Qw + M4;                     // 4M
    unsigned short* Vtw = Kw + M4;                     // 4M (transposed V)
    unsigned short* Zb  = xb;

    conv_fused<<<3072, 256, 0, stream>>>(x, WQ, WK, WV, WO, xb, Wt, WOt);

    dim3 g1(32, 24);
    qkv_mfma<<<g1, 256, 0, stream>>>(xb, Wt, bQ, bK, bV, Qw, Kw, Vtw);

    attn_mfma<<<512, 256, 0, stream>>>(Qw, Kw, Vtw, Zb);

    dim3 g3(64, 8);
    out_mfma<<<g3, 256, 0, stream>>>(Zb, WOt, bO, out);
}